// Round 6
// baseline (41.658 us; speedup 1.0000x reference)
//
#include <hip/hip_runtime.h>
#include <hip/hip_bf16.h>

#define B_ 8
#define T_ 2048
#define C_ 1024
#define HS_ 64

typedef float f32x4 __attribute__((ext_vector_type(4)));
typedef __bf16 bf16x8 __attribute__((ext_vector_type(8)));
typedef __bf16 bf16x4 __attribute__((ext_vector_type(4)));

// Workspaces:
//  wt[192][1024] bf16: rows 0-63 Wq^T (scaled 1/32), 64-127 Wk^T, 128-191 Wv^T
//  Qf[b*128+qt16][2 half][64 lane][8] : word = Q[qt*16+(lane&15)][half*32+(lane>>4)*8+j]
//  Kf identical mapping for K. Vf[b*64+kt32][4 ntv][64][8]:
//  word = V[kt32*32+(lane>>4)*8+j][ntv*16+(lane&15)]

// ---------------------------------------------------------------------------
// Kernel 1: W [1024][64] fp32 -> wt [192][1024] bf16 (transposed, q scaled).
// ---------------------------------------------------------------------------
__global__ __launch_bounds__(256) void wt_kernel(const float* __restrict__ Wq,
                                                 const float* __restrict__ Wk,
                                                 const float* __restrict__ Wv,
                                                 __bf16* __restrict__ wt) {
    __shared__ float tile[64][65];
    int mb = blockIdx.x >> 4;
    int k0 = (blockIdx.x & 15) * 64;
    const float* W = (mb == 0) ? Wq : (mb == 1 ? Wk : Wv);
    int c = threadIdx.x & 63;
#pragma unroll
    for (int r = threadIdx.x >> 6; r < 64; r += 4)
        tile[r][c] = W[(size_t)(k0 + r) * 64 + c];
    __syncthreads();
    float scale = (mb == 0) ? 0.03125f : 1.0f;
    int kk = threadIdx.x & 63;
#pragma unroll
    for (int n = threadIdx.x >> 6; n < 64; n += 4)
        wt[(size_t)(mb * 64 + n) * C_ + k0 + kk] = (__bf16)(tile[kk][n] * scale);
}

// ---------------------------------------------------------------------------
// Kernel 2: QKV GEMM. 512 blocks x 512 thr. Block: 64 rows x 96 cols
// (half h: cols h*96..h*96+95 of [q|k|v]), K-step 64, dual swizzled LDS
// (40KB -> up to 4 blocks/CU). XCD-paired bid mapping so both halves of the
// same 64 rows land on the same XCD L2. Wave w: m-tile w&3, nt (w>>2)*3..+2.
// ---------------------------------------------------------------------------
__global__ __launch_bounds__(512, 4) void qkv_kernel(const float* __restrict__ x,
                                                     const __bf16* __restrict__ wt,
                                                     __bf16* __restrict__ qf,
                                                     __bf16* __restrict__ kf,
                                                     __bf16* __restrict__ vf) {
    __shared__ __align__(16) char smem[40960];
    __bf16* xs0 = (__bf16*)smem;               // [64][64] swz, 8KB
    __bf16* xs1 = (__bf16*)(smem + 8192);
    __bf16* ws0 = (__bf16*)(smem + 16384);     // [96][64] swz, 12KB
    __bf16* ws1 = (__bf16*)(smem + 28672);

    const int tid = threadIdx.x;
    const int w = tid >> 6, lane = tid & 63, lq = lane & 15, lg = lane >> 4;
    // bid = g*16 + h*8 + xcd  ->  m-chunk g*8+xcd (same-XCD half pair)
    const int bid = blockIdx.x;
    const int m0 = ((bid >> 4) * 8 + (bid & 7)) * 64;
    const int n0 = ((bid >> 3) & 1) * 96;
    const int mt = w & 3;
    const int ntb = (w >> 2) * 3;

    f32x4 acc[3];
#pragma unroll
    for (int i = 0; i < 3; ++i) acc[i] = (f32x4)0.0f;

    const int xrow = tid >> 3, xch = tid & 7;
    float4 xr0, xr1;
    bf16x8 wr0, wr1;

    // prologue: load kt=0, fill buf0
    {
        const float* xp = x + (size_t)(m0 + xrow) * C_ + xch * 8;
        xr0 = *(const float4*)xp;
        xr1 = *(const float4*)(xp + 4);
        wr0 = *(const bf16x8*)(wt + (size_t)(n0 + (tid >> 3)) * C_ + (tid & 7) * 8);
        if (tid < 256) {
            int u = 512 + tid;
            wr1 = *(const bf16x8*)(wt + (size_t)(n0 + (u >> 3)) * C_ + (u & 7) * 8);
        }
        bf16x8 xb;
#pragma unroll
        for (int j = 0; j < 4; ++j) { xb[j] = (__bf16)xr0[j]; xb[4 + j] = (__bf16)xr1[j]; }
        *(bf16x8*)(xs0 + xrow * 64 + ((xch ^ (xrow & 7)) * 8)) = xb;
        int rw = tid >> 3, ch = tid & 7;
        *(bf16x8*)(ws0 + rw * 64 + ((ch ^ (rw & 7)) * 8)) = wr0;
        if (tid < 256) {
            int u = 512 + tid, rw1 = u >> 3, ch1 = u & 7;
            *(bf16x8*)(ws0 + rw1 * 64 + ((ch1 ^ (rw1 & 7)) * 8)) = wr1;
        }
    }

    for (int kt = 0; kt < 16; ++kt) {
        __syncthreads();
        __bf16* xsc = (kt & 1) ? xs1 : xs0;
        __bf16* wsc = (kt & 1) ? ws1 : ws0;
        if (kt < 15) {
            int k0 = (kt + 1) * 64;
            const float* xp = x + (size_t)(m0 + xrow) * C_ + k0 + xch * 8;
            xr0 = *(const float4*)xp;
            xr1 = *(const float4*)(xp + 4);
            wr0 = *(const bf16x8*)(wt + (size_t)(n0 + (tid >> 3)) * C_ + k0 + (tid & 7) * 8);
            if (tid < 256) {
                int u = 512 + tid;
                wr1 = *(const bf16x8*)(wt + (size_t)(n0 + (u >> 3)) * C_ + k0 + (u & 7) * 8);
            }
        }
#pragma unroll
        for (int ks = 0; ks < 2; ++ks) {
            int r = mt * 16 + lq;
            bf16x8 a = *(const bf16x8*)(xsc + r * 64 + (((ks * 4 + lg) ^ (r & 7)) * 8));
#pragma unroll
            for (int i = 0; i < 3; ++i) {
                int rw = (ntb + i) * 16 + lq;
                bf16x8 b = *(const bf16x8*)(wsc + rw * 64 + (((ks * 4 + lg) ^ (rw & 7)) * 8));
                acc[i] = __builtin_amdgcn_mfma_f32_16x16x32_bf16(a, b, acc[i], 0, 0, 0);
            }
        }
        if (kt < 15) {
            __bf16* xsn = (kt & 1) ? xs0 : xs1;
            __bf16* wsn = (kt & 1) ? ws0 : ws1;
            bf16x8 xb;
#pragma unroll
            for (int j = 0; j < 4; ++j) { xb[j] = (__bf16)xr0[j]; xb[4 + j] = (__bf16)xr1[j]; }
            *(bf16x8*)(xsn + xrow * 64 + ((xch ^ (xrow & 7)) * 8)) = xb;
            int rw = tid >> 3, ch = tid & 7;
            *(bf16x8*)(wsn + rw * 64 + ((ch ^ (rw & 7)) * 8)) = wr0;
            if (tid < 256) {
                int u = 512 + tid, rw1 = u >> 3, ch1 = u & 7;
                *(bf16x8*)(wsn + rw1 * 64 + ((ch1 ^ (rw1 & 7)) * 8)) = wr1;
            }
        }
    }
    __syncthreads();

    // epilogue: acc -> obuf [64][104] -> fragment stores
    __bf16(*obuf)[104] = (__bf16(*)[104])smem;
#pragma unroll
    for (int i = 0; i < 3; ++i)
#pragma unroll
        for (int r = 0; r < 4; ++r)
            obuf[mt * 16 + lg * 4 + r][(ntb + i) * 16 + lq] = (__bf16)acc[i][r];
    __syncthreads();

    if (n0 == 0) {
        // cols 0-63 = q, 64-95 = k half 0
        int mg = w & 3, hf = w >> 2;
        size_t qt16 = (size_t)(m0 >> 4) + mg;
        bf16x8 vq = *(const bf16x8*)&obuf[mg * 16 + lq][hf * 32 + lg * 8];
        *(bf16x8*)(qf + ((qt16 * 2 + hf) * 64 + lane) * 8) = vq;
        if (w < 4) {
            bf16x8 vk = *(const bf16x8*)&obuf[mg * 16 + lq][64 + lg * 8];
            *(bf16x8*)(kf + ((qt16 * 2 + 0) * 64 + lane) * 8) = vk;
        }
    } else {
        // cols 0-31 = k half 1, 32-95 = v
        if (w < 4) {
            int mg = w;
            size_t qt16 = (size_t)(m0 >> 4) + mg;
            bf16x8 vk = *(const bf16x8*)&obuf[mg * 16 + lq][lg * 8];
            *(bf16x8*)(kf + ((qt16 * 2 + 1) * 64 + lane) * 8) = vk;
        }
        int kl = w >> 2, ntv = w & 3;
        bf16x8 vv;
#pragma unroll
        for (int j = 0; j < 8; ++j)
            vv[j] = obuf[kl * 32 + lg * 8 + j][32 + ntv * 16 + lq];
        size_t kt32 = (size_t)(m0 >> 5) + kl;
        *(bf16x8*)(vf + ((kt32 * 4 + ntv) * 64 + lane) * 8) = vv;
    }
}

// ---------------------------------------------------------------------------
// Kernel 3: causal flash attention, swapped QK^T, KVBLK=64. 8 waves/block
// split 64-key tiles round-robin; one softmax combine per 64 keys; setprio
// around MFMA clusters; heavy tiles first; flash-combine via LDS.
// ---------------------------------------------------------------------------
__global__ __launch_bounds__(512) void attn_kernel(const __bf16* __restrict__ qf,
                                                   const __bf16* __restrict__ kf,
                                                   const __bf16* __restrict__ vf,
                                                   float* __restrict__ out) {
    __shared__ float olds[8][16][64];
    __shared__ float mlds[8][16], llds[8][16];
    __shared__ __align__(16) __bf16 plds[8][16 * 72];

    int w    = threadIdx.x >> 6;
    int lane = threadIdx.x & 63;
    int lq = lane & 15, lg = lane >> 4;

    int b  = blockIdx.x & 7;
    int t0 = (127 - (blockIdx.x >> 3)) * 16;   // heavy first

    size_t qbase = ((size_t)b * 128 + (t0 >> 4)) * 2;
    bf16x8 aq0 = *(const bf16x8*)(qf + ((qbase + 0) * 64 + lane) * 8);
    bf16x8 aq1 = *(const bf16x8*)(qf + ((qbase + 1) * 64 + lane) * 8);

    f32x4 o[4];
#pragma unroll
    for (int nt = 0; nt < 4; ++nt) o[nt] = (f32x4)0.0f;
    float m_s = -1e30f, l_s = 0.f;

    __bf16* pw = &plds[w][0];

    int ntiles = (t0 + 79) >> 6;   // ceil((t0+16)/64)
    for (int kt = w; kt < ntiles; kt += 8) {
        int s0 = kt * 64;
        f32x4 s[4];
        __builtin_amdgcn_s_setprio(1);
#pragma unroll
        for (int ct = 0; ct < 4; ++ct) {
            size_t kbase = ((size_t)b * 128 + (s0 >> 4) + ct) * 2;
            bf16x8 k0 = *(const bf16x8*)(kf + ((kbase + 0) * 64 + lane) * 8);
            bf16x8 k1 = *(const bf16x8*)(kf + ((kbase + 1) * 64 + lane) * 8);
            f32x4 a = (f32x4)0.0f;
            a = __builtin_amdgcn_mfma_f32_16x16x32_bf16(k0, aq0, a, 0, 0, 0);
            a = __builtin_amdgcn_mfma_f32_16x16x32_bf16(k1, aq1, a, 0, 0, 0);
            s[ct] = a;
        }
        __builtin_amdgcn_s_setprio(0);
        // causal mask: key = s0+ct*16+lg*4+r, query = t0+lq
        if (s0 + 63 > t0) {
#pragma unroll
            for (int ct = 0; ct < 4; ++ct)
#pragma unroll
                for (int r = 0; r < 4; ++r)
                    if (s0 + ct * 16 + lg * 4 + r > t0 + lq) s[ct][r] = -1e30f;
        }
        // per-lane softmax over 16 in-reg scores + cross-lg combine
        float pm = -1e30f;
#pragma unroll
        for (int ct = 0; ct < 4; ++ct)
#pragma unroll
            for (int r = 0; r < 4; ++r) pm = fmaxf(pm, s[ct][r]);
        pm = fmaxf(pm, __shfl_xor(pm, 16));
        pm = fmaxf(pm, __shfl_xor(pm, 32));
        float mn = fmaxf(m_s, pm);
        float al = __expf(m_s - mn);
        m_s = mn;
        f32x4 p[4];
        float rs = 0.f;
#pragma unroll
        for (int ct = 0; ct < 4; ++ct) {
#pragma unroll
            for (int r = 0; r < 4; ++r) {
                p[ct][r] = __expf(s[ct][r] - mn);
                rs += p[ct][r];
            }
        }
        rs += __shfl_xor(rs, 16);
        rs += __shfl_xor(rs, 32);
        l_s = l_s * al + rs;
        float alr[4];
#pragma unroll
        for (int r = 0; r < 4; ++r) alr[r] = __shfl(al, lg * 4 + r);
#pragma unroll
        for (int nt = 0; nt < 4; ++nt)
#pragma unroll
            for (int r = 0; r < 4; ++r) o[nt][r] *= alr[r];

        // P -> LDS: row = query lq, cols = 64 keys
#pragma unroll
        for (int ct = 0; ct < 4; ++ct) {
            bf16x4 qv;
#pragma unroll
            for (int r = 0; r < 4; ++r) qv[r] = (__bf16)p[ct][r];
            *(bf16x4*)&pw[lq * 72 + ct * 16 + lg * 4] = qv;
        }
        asm volatile("" ::: "memory");
        bf16x8 pa0 = *(const bf16x8*)&pw[lq * 72 + lg * 8];
        bf16x8 pa1 = *(const bf16x8*)&pw[lq * 72 + 32 + lg * 8];
        __builtin_amdgcn_s_setprio(1);
#pragma unroll
        for (int nt = 0; nt < 4; ++nt) {
            bf16x8 bv0 = *(const bf16x8*)(vf +
                (((size_t)(b * 64 + (s0 >> 5) + 0) * 4 + nt) * 64 + lane) * 8);
            o[nt] = __builtin_amdgcn_mfma_f32_16x16x32_bf16(pa0, bv0, o[nt], 0, 0, 0);
            bf16x8 bv1 = *(const bf16x8*)(vf +
                (((size_t)(b * 64 + (s0 >> 5) + 1) * 4 + nt) * 64 + lane) * 8);
            o[nt] = __builtin_amdgcn_mfma_f32_16x16x32_bf16(pa1, bv1, o[nt], 0, 0, 0);
        }
        __builtin_amdgcn_s_setprio(0);
    }

    asm volatile("" ::: "memory");
#pragma unroll
    for (int nt = 0; nt < 4; ++nt)
#pragma unroll
        for (int r = 0; r < 4; ++r)
            olds[w][lg * 4 + r][nt * 16 + lq] = o[nt][r];
    if (lg == 0) {
        mlds[w][lq] = m_s;
        llds[w][lq] = l_s;
    }
    __syncthreads();

    int row = threadIdx.x >> 5;
    int col = (threadIdx.x & 31) * 2;
    float M = -1e30f;
#pragma unroll
    for (int w2 = 0; w2 < 8; ++w2) M = fmaxf(M, mlds[w2][row]);
    float L = 0.f, o0 = 0.f, o1 = 0.f;
#pragma unroll
    for (int w2 = 0; w2 < 8; ++w2) {
        float sc = __expf(mlds[w2][row] - M);
        L  += sc * llds[w2][row];
        o0 += sc * olds[w2][row][col];
        o1 += sc * olds[w2][row][col + 1];
    }
    float inv = 1.0f / L;
    float* ob = out + ((size_t)b * T_ + t0 + row) * HS_ + col;
    ob[0] = o0 * inv;
    ob[1] = o1 * inv;
}

extern "C" void kernel_launch(void* const* d_in, const int* in_sizes, int n_in,
                              void* d_out, int out_size, void* d_ws, size_t ws_size,
                              hipStream_t stream) {
    const float* x  = (const float*)d_in[0];
    const float* Wq = (const float*)d_in[1];
    const float* Wk = (const float*)d_in[2];
    const float* Wv = (const float*)d_in[3];
    char* ws = (char*)d_ws;
    __bf16* wt = (__bf16*)ws;                     // 393216 B
    __bf16* qf = (__bf16*)(ws + 393216);          // 2 MB
    __bf16* kf = (__bf16*)(ws + 2490368);         // 2 MB
    __bf16* vf = (__bf16*)(ws + 4587520);         // 2 MB
    float* out = (float*)d_out;

    wt_kernel<<<dim3(48), dim3(256), 0, stream>>>(Wq, Wk, Wv, wt);
    qkv_kernel<<<dim3(512), dim3(512), 0, stream>>>(x, wt, qf, kf, vf);
    attn_kernel<<<dim3(1024), dim3(512), 0, stream>>>(qf, kf, vf, out);
}